// Round 8
// baseline (223.931 us; speedup 1.0000x reference)
//
#include <hip/hip_runtime.h>
#include <stdint.h>

#define KNN 16

typedef float vfloat4 __attribute__((ext_vector_type(4)));

// Map float to a uint32 whose unsigned order matches the float order
// (handles tiny negative dists from fp rounding).
__device__ __forceinline__ uint32_t fkey(float f) {
    uint32_t u = __float_as_uint(f);
    return (u & 0x80000000u) ? ~u : (u | 0x80000000u);
}

// Pack xyz_prev into (x, y, z, r2) float4 rows. r2 uses the exact fp32 op
// order of the reference (verified absmax 0 in R1-R4, R6, R7), so downstream
// distances are bit-identical.
__global__ __launch_bounds__(256) void prep_kernel(
    const float* __restrict__ xyz_prev, vfloat4* __restrict__ P, int n_prev)
{
    const int i = blockIdx.x * 256 + threadIdx.x;
    if (i >= n_prev) return;
    const float x = xyz_prev[3 * i + 0];
    const float y = xyz_prev[3 * i + 1];
    const float z = xyz_prev[3 * i + 2];
    const float r2 = __fadd_rn(__fadd_rn(__fmul_rn(x, x), __fmul_rn(y, y)),
                               __fmul_rn(z, z));
    vfloat4 v = {x, y, z, r2};
    P[i] = v;
}

// FUSED knn+combine, one wave per query. Phase 1 is the R7-verified KNN
// (wave-distributed sorted top-16 in lanes 0..15, u64 keys fkey(dist)<<32|idx
// == jax.lax.top_k stable order; tau = lane-15 key = EXACT running global
// 16th-best; 8-deep load batching; per-t ballot + serial shuffle-insert).
// Phase 2 broadcasts the 16 indices via __shfl (R4-verified) and runs the
// R3/R4-verified gather/diff/concat with nontemporal streaming stores.
// No scratch round-trip, no second launch, no grid-wide drain between phases.
__global__ __launch_bounds__(256) void fused_kernel(
    const vfloat4* __restrict__ P, const float* __restrict__ xyz_cur,
    const float* __restrict__ feat_prev, const float* __restrict__ feat_cur,
    float* __restrict__ out, int n_prev, int n_cur, int c4)
{
    const int lane = threadIdx.x & 63;
    const int q = blockIdx.x * 4 + (threadIdx.x >> 6);
    if (q >= n_cur) return;  // wave-uniform

    // ---------------- phase 1: exact KNN (R7 verbatim) ----------------
    const float qx = xyz_cur[3 * q + 0];
    const float qy = xyz_cur[3 * q + 1];
    const float qz = xyz_cur[3 * q + 2];
    // q2 is a per-query constant (cannot change the argsort); same op order.
    const float q2 = __fadd_rn(__fadd_rn(__fmul_rn(qx, qx), __fmul_rn(qy, qy)),
                               __fmul_rn(qz, qz));

    // warmup: bitonic sort of the first 64 candidates (ascending)
    unsigned long long v;
    {
        const int r = lane;
        const vfloat4 p = P[r < n_prev ? r : 0];
        const float cr = __fmaf_rn(p.z, qz, __fmaf_rn(p.y, qy, __fmul_rn(p.x, qx)));
        const float dist = __fsub_rn(__fadd_rn(q2, p.w), __fmul_rn(2.0f, cr));
        v = (r < n_prev)
            ? (((unsigned long long)fkey(dist) << 32) | (uint32_t)r)
            : ~0ull;
    }
#pragma unroll
    for (int k = 2; k <= 64; k <<= 1) {
#pragma unroll
        for (int j = k >> 1; j > 0; j >>= 1) {
            const unsigned long long o = __shfl_xor(v, j, 64);
            const bool keepMin = (((lane & k) == 0) == ((lane & j) == 0));
            const bool omin = o < v;
            v = (keepMin == omin) ? o : v;  // keepMin ? min(v,o) : max(v,o)
        }
    }
    unsigned long long lkey = (lane < KNN) ? v : ~0ull;
    unsigned long long tau = __shfl(lkey, 15, 64);  // EXACT running 16th-best

    const int n_iter = (n_prev + 63) >> 6;  // wave-uniform trip count
    int t = 1;
    for (; t + 7 < n_iter; t += 8) {
        vfloat4 pv[8];
#pragma unroll
        for (int u = 0; u < 8; ++u) {
            const int r = ((t + u) << 6) + lane;
            pv[u] = P[r < n_prev ? r : 0];
        }
#pragma unroll
        for (int u = 0; u < 8; ++u) {
            const int r = ((t + u) << 6) + lane;
            const vfloat4 p = pv[u];
            const float cr = __fmaf_rn(p.z, qz, __fmaf_rn(p.y, qy, __fmul_rn(p.x, qx)));
            const float dist = __fsub_rn(__fadd_rn(q2, p.w), __fmul_rn(2.0f, cr));
            const unsigned long long key = (r < n_prev)
                ? (((unsigned long long)fkey(dist) << 32) | (uint32_t)r)
                : ~0ull;
            unsigned long long mask = __ballot(key < tau);
            while (mask) {  // wave-uniform
                const int b = (int)__builtin_ctzll(mask);
                mask &= mask - 1;
                const unsigned long long bk = __shfl(key, b, 64);
                if (bk < tau) {  // re-check: tau may have tightened
                    const unsigned long long sh = __shfl_up(lkey, 1, 64);
                    unsigned long long nk;
                    if (lkey < bk) nk = lkey;                    // stays
                    else nk = (lane == 0 || sh < bk) ? bk : sh;  // insert/shift
                    if (lane < KNN) lkey = nk;
                    tau = __shfl(lkey, 15, 64);
                }
            }
        }
    }
    for (; t < n_iter; ++t) {  // tail: identical single-t body
        const int r = (t << 6) + lane;
        const vfloat4 p = P[r < n_prev ? r : 0];
        const float cr = __fmaf_rn(p.z, qz, __fmaf_rn(p.y, qy, __fmul_rn(p.x, qx)));
        const float dist = __fsub_rn(__fadd_rn(q2, p.w), __fmul_rn(2.0f, cr));
        const unsigned long long key = (r < n_prev)
            ? (((unsigned long long)fkey(dist) << 32) | (uint32_t)r)
            : ~0ull;
        unsigned long long mask = __ballot(key < tau);
        while (mask) {
            const int b = (int)__builtin_ctzll(mask);
            mask &= mask - 1;
            const unsigned long long bk = __shfl(key, b, 64);
            if (bk < tau) {
                const unsigned long long sh = __shfl_up(lkey, 1, 64);
                unsigned long long nk;
                if (lkey < bk) nk = lkey;
                else nk = (lane == 0 || sh < bk) ? bk : sh;
                if (lane < KNN) lkey = nk;
                tau = __shfl(lkey, 15, 64);
            }
        }
    }

    // Broadcast the 16 winning indices to all lanes (R4-verified).
    int nb[KNN];
#pragma unroll
    for (int j = 0; j < KNN; ++j)
        nb[j] = (int)(__shfl(lkey, j, 64) & 0xffffffffu);

    // ---------------- phase 2: gather + combine (R3/R4-verified) ----------
    const vfloat4* pbase = (const vfloat4*)feat_prev;
    const vfloat4* crow  = (const vfloat4*)feat_cur + (size_t)q * c4;
    const int c8 = 2 * c4;

    for (int i = lane; i < c4; i += 64) {
        const vfloat4 c = crow[i];
        vfloat4 p[KNN];
#pragma unroll
        for (int j = 0; j < KNN; ++j)
            p[j] = pbase[(size_t)nb[j] * c4 + i];

#pragma unroll
        for (int j = 0; j < KNN; ++j) {
            vfloat4* orow = (vfloat4*)out + (size_t)(q * KNN + j) * c8;
            __builtin_nontemporal_store(p[j] - c, orow + i);
            __builtin_nontemporal_store(c, orow + c4 + i);
        }
    }
}

extern "C" void kernel_launch(void* const* d_in, const int* in_sizes, int n_in,
                              void* d_out, int out_size, void* d_ws, size_t ws_size,
                              hipStream_t stream) {
    const float* xyz_prev  = (const float*)d_in[0];
    const float* xyz_cur   = (const float*)d_in[1];
    const float* feat_prev = (const float*)d_in[2];
    const float* feat_cur  = (const float*)d_in[3];
    float* out = (float*)d_out;

    const int n_prev = in_sizes[0] / 3;
    const int n_cur  = in_sizes[1] / 3;
    const int C      = in_sizes[2] / n_prev;   // 256

    // d_ws: packed (x,y,z,r2) table only — no index scratch needed when fused.
    vfloat4* P = (vfloat4*)d_ws;

    prep_kernel<<<(n_prev + 255) / 256, 256, 0, stream>>>(xyz_prev, P, n_prev);

    const int blocks = (n_cur + 3) / 4;        // 4 waves (queries) per block
    fused_kernel<<<blocks, 256, 0, stream>>>(P, xyz_cur, feat_prev, feat_cur,
                                             out, n_prev, n_cur, C / 4);
}

// Round 9
// 210.443 us; speedup vs baseline: 1.0641x; 1.0641x over previous
//
#include <hip/hip_runtime.h>
#include <stdint.h>

#define KNN 16
#define CHUNK 2048  // points staged per block-iteration (32 KB LDS)

typedef float vfloat4 __attribute__((ext_vector_type(4)));

// Map float to a uint32 whose unsigned order matches the float order
// (handles tiny negative dists from fp rounding).
__device__ __forceinline__ uint32_t fkey(float f) {
    uint32_t u = __float_as_uint(f);
    return (u & 0x80000000u) ? ~u : (u | 0x80000000u);
}

// Pack xyz_prev into (x, y, z, r2) float4 rows. r2 uses the exact fp32 op
// order of the reference (verified absmax 0 in R1-R4, R6-R8), so downstream
// distances are bit-identical.
__global__ __launch_bounds__(256) void prep_kernel(
    const float* __restrict__ xyz_prev, vfloat4* __restrict__ P, int n_prev)
{
    const int i = blockIdx.x * 256 + threadIdx.x;
    if (i >= n_prev) return;
    const float x = xyz_prev[3 * i + 0];
    const float y = xyz_prev[3 * i + 1];
    const float z = xyz_prev[3 * i + 2];
    const float r2 = __fadd_rn(__fadd_rn(__fmul_rn(x, x), __fmul_rn(y, y)),
                               __fmul_rn(z, z));
    vfloat4 v = {x, y, z, r2};
    P[i] = v;
}

// Block-cooperative KNN: 4 waves (4 queries) per block SHARE staged P-chunks
// in LDS (cuts global P traffic 4x; replaces per-wave L1/L2 line processing
// with LDS reads). Per wave, the R6/R7-VERIFIED wave-distributed sorted
// top-16 (lanes 0..15, u64 keys fkey(dist)<<32|idx == jax.lax.top_k stable
// order; tau = lane-15 key = EXACT running global 16th-best; per-t ballot +
// serial shuffle-insert). No early return: clamped query + store guard so all
// waves reach every __syncthreads.
__global__ __launch_bounds__(256) void knn_kernel(
    const vfloat4* __restrict__ P, const float* __restrict__ xyz_cur,
    int* __restrict__ knn_idx, int n_prev, int n_cur)
{
    __shared__ vfloat4 tile[CHUNK];
    const int lane = threadIdx.x & 63;
    const int q = blockIdx.x * 4 + (threadIdx.x >> 6);
    const bool active = (q < n_cur);
    const int qc = active ? q : (n_cur - 1);  // clamp: compute, don't store

    const float qx = xyz_cur[3 * qc + 0];
    const float qy = xyz_cur[3 * qc + 1];
    const float qz = xyz_cur[3 * qc + 2];
    // q2 is a per-query constant (cannot change the argsort); same op order.
    const float q2 = __fadd_rn(__fadd_rn(__fmul_rn(qx, qx), __fmul_rn(qy, qy)),
                               __fmul_rn(qz, qz));

    unsigned long long lkey = ~0ull;
    unsigned long long tau = ~0ull;
    bool warmed = false;

    const int n_chunks = (n_prev + CHUNK - 1) / CHUNK;
    for (int chunk = 0; chunk < n_chunks; ++chunk) {
        const int base = chunk * CHUNK;
        // ---- cooperative stage: 256 threads x (CHUNK/256) float4 ----
#pragma unroll
        for (int k = 0; k < CHUNK / 256; ++k) {
            const int li = (k << 8) + threadIdx.x;
            const int gi = base + li;
            tile[li] = P[gi < n_prev ? gi : 0];
        }
        __syncthreads();

        const int iters = (CHUNK + 63) >> 6;  // 32 wave-iterations per chunk
        int i0 = 0;

        if (!warmed) {
            // warmup: bitonic sort of the first 64 candidates (ascending),
            // from LDS (values unchanged vs global — bit-identical keys).
            const int r = base + lane;
            const vfloat4 p = tile[lane];
            const float cr = __fmaf_rn(p.z, qz, __fmaf_rn(p.y, qy, __fmul_rn(p.x, qx)));
            const float dist = __fsub_rn(__fadd_rn(q2, p.w), __fmul_rn(2.0f, cr));
            unsigned long long v = (r < n_prev)
                ? (((unsigned long long)fkey(dist) << 32) | (uint32_t)r)
                : ~0ull;
#pragma unroll
            for (int k = 2; k <= 64; k <<= 1) {
#pragma unroll
                for (int j = k >> 1; j > 0; j >>= 1) {
                    const unsigned long long o = __shfl_xor(v, j, 64);
                    const bool keepMin = (((lane & k) == 0) == ((lane & j) == 0));
                    const bool omin = o < v;
                    v = (keepMin == omin) ? o : v;  // keepMin ? min : max
                }
            }
            lkey = (lane < KNN) ? v : ~0ull;
            tau = __shfl(lkey, 15, 64);  // EXACT running 16th-best
            warmed = true;
            i0 = 1;
        }

        // ---- consume: groups of 4 wave-iterations (4-deep ds_read batch),
        //      each t processed with the verified ballot+insert body ----
        int i = i0;
        for (; i + 3 < iters; i += 4) {
            vfloat4 pv[4];
#pragma unroll
            for (int u = 0; u < 4; ++u)
                pv[u] = tile[((i + u) << 6) + lane];
#pragma unroll
            for (int u = 0; u < 4; ++u) {
                const int r = base + ((i + u) << 6) + lane;
                const vfloat4 p = pv[u];
                const float cr = __fmaf_rn(p.z, qz, __fmaf_rn(p.y, qy, __fmul_rn(p.x, qx)));
                const float dist = __fsub_rn(__fadd_rn(q2, p.w), __fmul_rn(2.0f, cr));
                const unsigned long long key = (r < n_prev)
                    ? (((unsigned long long)fkey(dist) << 32) | (uint32_t)r)
                    : ~0ull;
                unsigned long long mask = __ballot(key < tau);
                while (mask) {  // wave-uniform
                    const int b = (int)__builtin_ctzll(mask);
                    mask &= mask - 1;
                    const unsigned long long bk = __shfl(key, b, 64);
                    if (bk < tau) {  // re-check: tau may have tightened
                        const unsigned long long sh = __shfl_up(lkey, 1, 64);
                        unsigned long long nk;
                        if (lkey < bk) nk = lkey;                    // stays
                        else nk = (lane == 0 || sh < bk) ? bk : sh;  // insert/shift
                        if (lane < KNN) lkey = nk;
                        tau = __shfl(lkey, 15, 64);
                    }
                }
            }
        }
        for (; i < iters; ++i) {  // tail: identical single-t body
            const int r = base + (i << 6) + lane;
            const vfloat4 p = tile[(i << 6) + lane];
            const float cr = __fmaf_rn(p.z, qz, __fmaf_rn(p.y, qy, __fmul_rn(p.x, qx)));
            const float dist = __fsub_rn(__fadd_rn(q2, p.w), __fmul_rn(2.0f, cr));
            const unsigned long long key = (r < n_prev)
                ? (((unsigned long long)fkey(dist) << 32) | (uint32_t)r)
                : ~0ull;
            unsigned long long mask = __ballot(key < tau);
            while (mask) {
                const int b = (int)__builtin_ctzll(mask);
                mask &= mask - 1;
                const unsigned long long bk = __shfl(key, b, 64);
                if (bk < tau) {
                    const unsigned long long sh = __shfl_up(lkey, 1, 64);
                    unsigned long long nk;
                    if (lkey < bk) nk = lkey;
                    else nk = (lane == 0 || sh < bk) ? bk : sh;
                    if (lane < KNN) lkey = nk;
                    tau = __shfl(lkey, 15, 64);
                }
            }
        }
        __syncthreads();  // before next chunk overwrites the tile
    }

    if (active && lane < KNN)
        knn_idx[q * KNN + lane] = (int)(lkey & 0xffffffffu);
}

// R7-verified combine, verbatim: one wave per (query, neighbor-group-of-4).
// Coverage: w in [0, 4*n_cur) -> q = w>>2, jg = (w&3)*4; rows q*16+jg+{0..3}
// — every output row exactly once. Nontemporal stores keep the 134 MB write
// stream from evicting the 8 MB gather table out of L2/LLC.
__global__ __launch_bounds__(256) void combine_kernel(
    const float* __restrict__ feat_prev, const float* __restrict__ feat_cur,
    const int* __restrict__ knn_idx, float* __restrict__ out,
    int n_cur, int c4)
{
    const int w = blockIdx.x * 4 + (threadIdx.x >> 6);
    const int lane = threadIdx.x & 63;
    const int q = w >> 2;
    const int jg = (w & 3) * 4;
    if (q >= n_cur) return;

    int nb[4];
#pragma unroll
    for (int j = 0; j < 4; ++j)
        nb[j] = knn_idx[q * KNN + jg + j];

    const vfloat4* pbase = (const vfloat4*)feat_prev;
    const vfloat4* crow  = (const vfloat4*)feat_cur + (size_t)q * c4;
    const int c8 = 2 * c4;

    for (int i = lane; i < c4; i += 64) {
        const vfloat4 c = crow[i];
        vfloat4 p[4];
#pragma unroll
        for (int j = 0; j < 4; ++j)
            p[j] = pbase[(size_t)nb[j] * c4 + i];

#pragma unroll
        for (int j = 0; j < 4; ++j) {
            vfloat4* orow = (vfloat4*)out + (size_t)(q * KNN + jg + j) * c8;
            __builtin_nontemporal_store(p[j] - c, orow + i);
            __builtin_nontemporal_store(c, orow + c4 + i);
        }
    }
}

extern "C" void kernel_launch(void* const* d_in, const int* in_sizes, int n_in,
                              void* d_out, int out_size, void* d_ws, size_t ws_size,
                              hipStream_t stream) {
    const float* xyz_prev  = (const float*)d_in[0];
    const float* xyz_cur   = (const float*)d_in[1];
    const float* feat_prev = (const float*)d_in[2];
    const float* feat_cur  = (const float*)d_in[3];
    float* out = (float*)d_out;

    const int n_prev = in_sizes[0] / 3;
    const int n_cur  = in_sizes[1] / 3;
    const int C      = in_sizes[2] / n_prev;   // 256

    // d_ws layout: [0, 16*n_prev) packed (x,y,z,r2) table; then knn indices.
    vfloat4* P = (vfloat4*)d_ws;
    int* knn = (int*)((char*)d_ws + (size_t)n_prev * sizeof(vfloat4));

    prep_kernel<<<(n_prev + 255) / 256, 256, 0, stream>>>(xyz_prev, P, n_prev);

    const int knn_blocks = (n_cur + 3) / 4;    // 4 queries (waves) per block
    knn_kernel<<<knn_blocks, 256, 0, stream>>>(P, xyz_cur, knn, n_prev, n_cur);

    const int n_waves = n_cur * 4;             // 4 neighbor-rows per wave
    combine_kernel<<<(n_waves + 3) / 4, 256, 0, stream>>>(feat_prev, feat_cur,
                                                          knn, out, n_cur, C / 4);
}

// Round 10
// 202.049 us; speedup vs baseline: 1.1083x; 1.0415x over previous
//
#include <hip/hip_runtime.h>
#include <stdint.h>

#define KNN 16

typedef float vfloat4 __attribute__((ext_vector_type(4)));

// Map float to a uint32 whose unsigned order matches the float order
// (handles tiny negative dists from fp rounding).
__device__ __forceinline__ uint32_t fkey(float f) {
    uint32_t u = __float_as_uint(f);
    return (u & 0x80000000u) ? ~u : (u | 0x80000000u);
}

// u64 broadcast from wave-uniform lane l: two v_readlane (no DS-pipe traffic,
// unlike __shfl which lowers to 2x ds_bpermute_b32).
__device__ __forceinline__ unsigned long long bcast64(unsigned long long x, int l) {
    const uint32_t lo = (uint32_t)__builtin_amdgcn_readlane((int)(uint32_t)x, l);
    const uint32_t hi = (uint32_t)__builtin_amdgcn_readlane((int)(uint32_t)(x >> 32), l);
    return ((unsigned long long)hi << 32) | lo;
}

// u64 lane shift-up-by-1 within each 16-lane DPP row (row_shr:1 = 0x111).
// Lanes 1..15 get lane-1..14's value — identical to __shfl_up(x,1) there;
// lane 0 gets 0 (bound_ctrl), which callers mask via an explicit lane==0
// select; lanes >=16 are discarded by the lane<16 list guard. VALU-only.
__device__ __forceinline__ unsigned long long shup1_64(unsigned long long x) {
    const uint32_t lo = (uint32_t)__builtin_amdgcn_update_dpp(
        0, (int)(uint32_t)x, 0x111, 0xF, 0xF, true);
    const uint32_t hi = (uint32_t)__builtin_amdgcn_update_dpp(
        0, (int)(uint32_t)(x >> 32), 0x111, 0xF, 0xF, true);
    return ((unsigned long long)hi << 32) | lo;
}

// Pack xyz_prev into (x, y, z, r2) float4 rows. r2 uses the exact fp32 op
// order of the reference (verified absmax 0 in R1-R4, R6-R9), so downstream
// distances are bit-identical.
__global__ __launch_bounds__(256) void prep_kernel(
    const float* __restrict__ xyz_prev, vfloat4* __restrict__ P, int n_prev)
{
    const int i = blockIdx.x * 256 + threadIdx.x;
    if (i >= n_prev) return;
    const float x = xyz_prev[3 * i + 0];
    const float y = xyz_prev[3 * i + 1];
    const float z = xyz_prev[3 * i + 2];
    const float r2 = __fadd_rn(__fadd_rn(__fmul_rn(x, x), __fmul_rn(y, y)),
                               __fmul_rn(z, z));
    vfloat4 v = {x, y, z, r2};
    P[i] = v;
}

// One wave per query. R7-verified structure (global 8-deep load batching,
// per-t ballot + serial insert into the wave-distributed sorted top-16 in
// lanes 0..15; u64 keys fkey(dist)<<32|idx == jax.lax.top_k stable order;
// tau = lane-15 key = EXACT running global 16th-best). Only delta vs R7:
// the insert's three u64 __shfl's (6 ds_bpermute each insert, DS-pipe bound
// per R8/R9 evidence) are replaced by v_readlane broadcasts + a DPP row_shr:1
// shift — zero DS ops per insert, same values moved.
__global__ __launch_bounds__(256) void knn_kernel(
    const vfloat4* __restrict__ P, const float* __restrict__ xyz_cur,
    int* __restrict__ knn_idx, int n_prev, int n_cur)
{
    const int lane = threadIdx.x & 63;
    const int q = blockIdx.x * 4 + (threadIdx.x >> 6);
    if (q >= n_cur) return;  // wave-uniform

    const float qx = xyz_cur[3 * q + 0];
    const float qy = xyz_cur[3 * q + 1];
    const float qz = xyz_cur[3 * q + 2];
    // q2 is a per-query constant (cannot change the argsort); same op order.
    const float q2 = __fadd_rn(__fadd_rn(__fmul_rn(qx, qx), __fmul_rn(qy, qy)),
                               __fmul_rn(qz, qz));

    // ---- warmup: bitonic sort of the first 64 candidates (ascending) ----
    unsigned long long v;
    {
        const int r = lane;
        const vfloat4 p = P[r < n_prev ? r : 0];
        const float cr = __fmaf_rn(p.z, qz, __fmaf_rn(p.y, qy, __fmul_rn(p.x, qx)));
        const float dist = __fsub_rn(__fadd_rn(q2, p.w), __fmul_rn(2.0f, cr));
        v = (r < n_prev)
            ? (((unsigned long long)fkey(dist) << 32) | (uint32_t)r)
            : ~0ull;
    }
#pragma unroll
    for (int k = 2; k <= 64; k <<= 1) {
#pragma unroll
        for (int j = k >> 1; j > 0; j >>= 1) {
            const unsigned long long o = __shfl_xor(v, j, 64);
            const bool keepMin = (((lane & k) == 0) == ((lane & j) == 0));
            const bool omin = o < v;
            v = (keepMin == omin) ? o : v;  // keepMin ? min(v,o) : max(v,o)
        }
    }
    unsigned long long lkey = (lane < KNN) ? v : ~0ull;
    unsigned long long tau = bcast64(lkey, 15);  // EXACT running 16th-best

    const int n_iter = (n_prev + 63) >> 6;  // wave-uniform trip count
    int t = 1;
    // main: groups of 8 iterations, loads issued up front (8-deep MLP),
    // then each t processed with the verified ballot+insert body.
    for (; t + 7 < n_iter; t += 8) {
        vfloat4 pv[8];
#pragma unroll
        for (int u = 0; u < 8; ++u) {
            const int r = ((t + u) << 6) + lane;
            pv[u] = P[r < n_prev ? r : 0];
        }
#pragma unroll
        for (int u = 0; u < 8; ++u) {
            const int r = ((t + u) << 6) + lane;
            const vfloat4 p = pv[u];
            const float cr = __fmaf_rn(p.z, qz, __fmaf_rn(p.y, qy, __fmul_rn(p.x, qx)));
            const float dist = __fsub_rn(__fadd_rn(q2, p.w), __fmul_rn(2.0f, cr));
            const unsigned long long key = (r < n_prev)
                ? (((unsigned long long)fkey(dist) << 32) | (uint32_t)r)
                : ~0ull;
            unsigned long long mask = __ballot(key < tau);
            while (mask) {  // wave-uniform
                const int b = (int)__builtin_ctzll(mask);
                mask &= mask - 1;
                const unsigned long long bk = bcast64(key, b);
                if (bk < tau) {  // re-check: tau may have tightened (uniform)
                    const unsigned long long sh = shup1_64(lkey);
                    unsigned long long nk;
                    if (lkey < bk) nk = lkey;                    // stays
                    else nk = (lane == 0 || sh < bk) ? bk : sh;  // insert/shift
                    tau = bcast64(nk, 15);  // nk computed by all 64 lanes
                    if (lane < KNN) lkey = nk;
                }
            }
        }
    }
    // tail: identical single-t body
    for (; t < n_iter; ++t) {
        const int r = (t << 6) + lane;
        const vfloat4 p = P[r < n_prev ? r : 0];
        const float cr = __fmaf_rn(p.z, qz, __fmaf_rn(p.y, qy, __fmul_rn(p.x, qx)));
        const float dist = __fsub_rn(__fadd_rn(q2, p.w), __fmul_rn(2.0f, cr));
        const unsigned long long key = (r < n_prev)
            ? (((unsigned long long)fkey(dist) << 32) | (uint32_t)r)
            : ~0ull;
        unsigned long long mask = __ballot(key < tau);
        while (mask) {
            const int b = (int)__builtin_ctzll(mask);
            mask &= mask - 1;
            const unsigned long long bk = bcast64(key, b);
            if (bk < tau) {
                const unsigned long long sh = shup1_64(lkey);
                unsigned long long nk;
                if (lkey < bk) nk = lkey;
                else nk = (lane == 0 || sh < bk) ? bk : sh;
                tau = bcast64(nk, 15);
                if (lane < KNN) lkey = nk;
            }
        }
    }

    if (lane < KNN)
        knn_idx[q * KNN + lane] = (int)(lkey & 0xffffffffu);
}

// R7-verified combine, verbatim: one wave per (query, neighbor-group-of-4).
// Coverage: w in [0, 4*n_cur) -> q = w>>2, jg = (w&3)*4; rows q*16+jg+{0..3}
// — every output row exactly once. Nontemporal stores keep the 134 MB write
// stream from evicting the 8 MB gather table out of L2/LLC.
__global__ __launch_bounds__(256) void combine_kernel(
    const float* __restrict__ feat_prev, const float* __restrict__ feat_cur,
    const int* __restrict__ knn_idx, float* __restrict__ out,
    int n_cur, int c4)
{
    const int w = blockIdx.x * 4 + (threadIdx.x >> 6);
    const int lane = threadIdx.x & 63;
    const int q = w >> 2;
    const int jg = (w & 3) * 4;
    if (q >= n_cur) return;

    int nb[4];
#pragma unroll
    for (int j = 0; j < 4; ++j)
        nb[j] = knn_idx[q * KNN + jg + j];

    const vfloat4* pbase = (const vfloat4*)feat_prev;
    const vfloat4* crow  = (const vfloat4*)feat_cur + (size_t)q * c4;
    const int c8 = 2 * c4;

    for (int i = lane; i < c4; i += 64) {
        const vfloat4 c = crow[i];
        vfloat4 p[4];
#pragma unroll
        for (int j = 0; j < 4; ++j)
            p[j] = pbase[(size_t)nb[j] * c4 + i];

#pragma unroll
        for (int j = 0; j < 4; ++j) {
            vfloat4* orow = (vfloat4*)out + (size_t)(q * KNN + jg + j) * c8;
            __builtin_nontemporal_store(p[j] - c, orow + i);
            __builtin_nontemporal_store(c, orow + c4 + i);
        }
    }
}

extern "C" void kernel_launch(void* const* d_in, const int* in_sizes, int n_in,
                              void* d_out, int out_size, void* d_ws, size_t ws_size,
                              hipStream_t stream) {
    const float* xyz_prev  = (const float*)d_in[0];
    const float* xyz_cur   = (const float*)d_in[1];
    const float* feat_prev = (const float*)d_in[2];
    const float* feat_cur  = (const float*)d_in[3];
    float* out = (float*)d_out;

    const int n_prev = in_sizes[0] / 3;
    const int n_cur  = in_sizes[1] / 3;
    const int C      = in_sizes[2] / n_prev;   // 256

    // d_ws layout: [0, 16*n_prev) packed (x,y,z,r2) table; then knn indices.
    vfloat4* P = (vfloat4*)d_ws;
    int* knn = (int*)((char*)d_ws + (size_t)n_prev * sizeof(vfloat4));

    prep_kernel<<<(n_prev + 255) / 256, 256, 0, stream>>>(xyz_prev, P, n_prev);

    const int knn_blocks = (n_cur + 3) / 4;    // 4 queries (waves) per block
    knn_kernel<<<knn_blocks, 256, 0, stream>>>(P, xyz_cur, knn, n_prev, n_cur);

    const int n_waves = n_cur * 4;             // 4 neighbor-rows per wave
    combine_kernel<<<(n_waves + 3) / 4, 256, 0, stream>>>(feat_prev, feat_cur,
                                                          knn, out, n_cur, C / 4);
}